// Round 10
// baseline (808.992 us; speedup 1.0000x reference)
//
#include <hip/hip_runtime.h>
#include <hip/hip_bf16.h>

#define NN     50000
#define NN2    100000
#define NEDGE  1600000
#define NE2    3200000
#define NG     512
#define FIN    128
#define FHID   128
#define FPROJ  256

// merged radix CSR build params — 512-node coarse buckets
#define BSH    9
#define BSZ    512
#define NBUCK  98
#define NBUCK2 196
#define EPB    8192
#define NABLK  196
#define NABLK2 392
#define NHIST2 (NBUCK2*NABLK2)   // 76,832

typedef __attribute__((ext_vector_type(8))) short short8;
typedef __attribute__((ext_vector_type(4))) float f32x4;

static __device__ __forceinline__ short f2bf(float f) {
    union { float f; unsigned u; } x; x.f = f;
    unsigned r = (x.u + 0x7FFFu + ((x.u >> 16) & 1u)) >> 16;
    return (short)(r & 0xFFFFu);
}
static __device__ __forceinline__ float bf2f(unsigned short u) {
    union { unsigned u; float f; } x; x.u = ((unsigned)u) << 16;
    return x.f;
}
static __device__ __forceinline__ float bflo(unsigned u) {
    union { unsigned u; float f; } x; x.u = u << 16; return x.f;
}
static __device__ __forceinline__ float bfhi(unsigned u) {
    union { unsigned u; float f; } x; x.u = u & 0xFFFF0000u; return x.f;
}
static __device__ __forceinline__ unsigned packbf(float a, float b) {
    return (unsigned)(unsigned short)f2bf(a) | ((unsigned)(unsigned short)f2bf(b) << 16);
}

// ---------------- merged CSR build (both graphs, atomic-free at device scope) ----

__global__ __launch_bounds__(1024) void k_bhist(const int* __restrict__ dst0,
                                                const int* __restrict__ dst1,
                                                int* __restrict__ histG,
                                                unsigned short* __restrict__ lrank) {
    __shared__ int h[NBUCK2];
    for (int j = threadIdx.x; j < NBUCK2; j += 1024) h[j] = 0;
    __syncthreads();
    int b = blockIdx.x;                  // 0..391
    int g = b / NABLK, blk = b % NABLK;
    const int* dst = g ? dst1 : dst0;
    int base = blk * EPB;
    int gb = g * NBUCK;
    for (int t = threadIdx.x; t < EPB; t += 1024) {
        int i = base + t;
        if (i < NEDGE)
            lrank[(size_t)g * NEDGE + i] =
                (unsigned short)atomicAdd(&h[gb + (dst[i] >> BSH)], 1);
    }
    __syncthreads();
    for (int j = threadIdx.x; j < NBUCK2; j += 1024)
        histG[(size_t)j * NABLK2 + b] = h[j];
}

// single-block exclusive scan of 76,832 ints (replaces 5-kernel cascade)
__global__ __launch_bounds__(1024) void s_scan_all(const int* __restrict__ in,
                                                   int* __restrict__ out, int n) {
    __shared__ int s[1024];
    int chunk = (n + 1023) / 1024;
    int b = threadIdx.x * chunk;
    int e = b + chunk; if (e > n) e = n;
    int sum = 0;
    for (int i = b; i < e; ++i) sum += in[i];
    s[threadIdx.x] = sum;
    for (int o = 1; o < 1024; o <<= 1) {
        __syncthreads();
        int t = (threadIdx.x >= o) ? s[threadIdx.x - o] : 0;
        __syncthreads();
        s[threadIdx.x] += t;
    }
    __syncthreads();
    int run = s[threadIdx.x] - sum;      // exclusive prefix of this chunk
    for (int i = b; i < e; ++i) { int v = in[i]; out[i] = run; run += v; }
}

__global__ __launch_bounds__(1024) void k_part(const int* __restrict__ src0,
                                               const int* __restrict__ dst0,
                                               const int* __restrict__ src1,
                                               const int* __restrict__ dst1,
                                               const unsigned short* __restrict__ lrank,
                                               const int* __restrict__ histS,
                                               unsigned* __restrict__ pedge) {
    int b = blockIdx.x;
    int g = b / NABLK, blk = b % NABLK;
    const int* src = g ? src1 : src0;
    const int* dst = g ? dst1 : dst0;
    int base = blk * EPB;
    int gb = g * NBUCK;
    for (int t = threadIdx.x; t < EPB; t += 1024) {
        int i = base + t;
        if (i < NEDGE) {
            int d = dst[i];
            int pos = histS[(size_t)(gb + (d >> BSH)) * NABLK2 + b]
                      + (int)lrank[(size_t)g * NEDGE + i];
            pedge[pos] = (unsigned)src[i] | ((unsigned)(d & (BSZ - 1)) << 16);
        }
    }
}

// one block per 512-node bucket -> fine CSR (ushort srcs) + csroff + dinv
__global__ __launch_bounds__(256) void k_csr(const unsigned* __restrict__ pedge,
                                             const int* __restrict__ histS,
                                             int* __restrict__ csroff,
                                             unsigned short* __restrict__ csrc,
                                             float* __restrict__ dinv) {
    __shared__ int cnt[BSZ], off[BSZ], cur[BSZ];
    int k = blockIdx.x;                  // 0..195
    int g = k / NBUCK;
    int nl0 = (k - g * NBUCK) * BSZ;
    int beg = histS[(size_t)k * NABLK2];
    int end = (k == NBUCK2 - 1) ? NE2 : histS[(size_t)(k + 1) * NABLK2];
    for (int t = threadIdx.x; t < BSZ; t += 256) { cnt[t] = 0; cur[t] = 0; }
    __syncthreads();
    for (int e = beg + threadIdx.x; e < end; e += 256)
        atomicAdd(&cnt[(pedge[e] >> 16) & (BSZ - 1)], 1);
    __syncthreads();
    if (threadIdx.x == 0) {
        int s = 0;
        for (int j = 0; j < BSZ; ++j) { off[j] = s; s += cnt[j]; }
    }
    __syncthreads();
    for (int e = beg + threadIdx.x; e < end; e += 256) {
        unsigned v = pedge[e];
        int j = (v >> 16) & (BSZ - 1);
        int r = atomicAdd(&cur[j], 1);
        csrc[beg + off[j] + r] = (unsigned short)(v & 0xFFFFu);
    }
    __syncthreads();
    for (int t = threadIdx.x; t < BSZ; t += 256) {
        int nl = nl0 + t;
        if (nl < NN) {
            int gn = g * NN + nl;
            csroff[gn] = beg + off[t];
            dinv[gn] = 1.0f / sqrtf((float)(cnt[t] + 1));
        }
    }
    if (k == NBUCK2 - 1 && threadIdx.x == 0) csroff[NN2] = NE2;
}

// ---------------- MFMA GEMM over both graphs: hp[i,:] = bf16((A[i,:]@W)*dinv[i]) ----

__global__ void k_prepw(const float* __restrict__ W0, const float* __restrict__ W1,
                        const float* __restrict__ W2, short* __restrict__ Wf) {
    int b = blockIdx.x;                  // 96 blocks
    int l = b >> 5; b &= 31;
    const float* W = (l == 0) ? W0 : (l == 1) ? W1 : W2;
    int nt = b >> 2, kt = b & 3;
    int lane = threadIdx.x;
    int n = nt * 16 + (lane & 15);
    int kbase = kt * 32 + (lane >> 4) * 8;
    short8 v;
#pragma unroll
    for (int j = 0; j < 8; ++j) v[j] = f2bf(W[(kbase + j) * FHID + n]);
    *(short8*)(Wf + (size_t)l * 16384 + (size_t)((nt * 4 + kt) * 64 + lane) * 8) = v;
}

__global__ __launch_bounds__(256) void k_gemm(const float* __restrict__ x1,
                                              const float* __restrict__ x2,
                                              const unsigned short* __restrict__ Abf,
                                              const short* __restrict__ Wf,
                                              const float* __restrict__ dinv,
                                              unsigned short* __restrict__ hp) {
    int lane = threadIdx.x & 63;
    int wv = threadIdx.x >> 6;
    int quad = lane >> 4;
    int rowbase = blockIdx.x * 64 + wv * 16;    // 1564 blocks -> 100,096 rows
    int arow = rowbase + (lane & 15);
    if (arow >= NN2) arow = NN2 - 1;

    f32x4 acc[8];
#pragma unroll
    for (int i = 0; i < 8; ++i) acc[i] = (f32x4){0.f, 0.f, 0.f, 0.f};

#pragma unroll
    for (int kt = 0; kt < 4; ++kt) {
        short8 af;
        if (Abf) {
            af = *(const short8*)(Abf + (size_t)arow * FIN + kt * 32 + quad * 8);
        } else {
            const float* ap = (arow < NN ? x1 + (size_t)arow * FIN
                                         : x2 + (size_t)(arow - NN) * FIN)
                              + kt * 32 + quad * 8;
            float4 a0 = *(const float4*)ap;
            float4 a1 = *(const float4*)(ap + 4);
            af[0] = f2bf(a0.x); af[1] = f2bf(a0.y); af[2] = f2bf(a0.z); af[3] = f2bf(a0.w);
            af[4] = f2bf(a1.x); af[5] = f2bf(a1.y); af[6] = f2bf(a1.z); af[7] = f2bf(a1.w);
        }
#pragma unroll
        for (int nt = 0; nt < 8; ++nt) {
            short8 bf = *(const short8*)(Wf + (size_t)((nt * 4 + kt) * 64 + lane) * 8);
            acc[nt] = __builtin_amdgcn_mfma_f32_16x16x32_bf16(af, bf, acc[nt], 0, 0, 0);
        }
    }
    // C/D layout: col = lane&15, row = quad*4 + reg   [measured m89/m91]
    float4 dv = *(const float4*)(dinv + rowbase + quad * 4);
    float dvv[4] = {dv.x, dv.y, dv.z, dv.w};
    int col = lane & 15;
#pragma unroll
    for (int r = 0; r < 4; ++r) {
        int orow = rowbase + quad * 4 + r;
        if (orow < NN2) {
#pragma unroll
            for (int nt = 0; nt < 8; ++nt)
                hp[(size_t)orow * FHID + nt * 16 + col] =
                    (unsigned short)f2bf(acc[nt][r] * dvv[r]);
        }
    }
}

// ------- Aggregate full 128-feature row, BOTH graphs in one dispatch
// blocks 0..6249 -> graph0, 6250..12499 -> graph1 (dispatch order keeps phases separate)

__global__ __launch_bounds__(256) void k_agg(const uint2* __restrict__ hp,
                                             const int* __restrict__ off,
                                             const unsigned short* __restrict__ csrc,
                                             const float* __restrict__ dinv,
                                             const float* __restrict__ bias,
                                             const unsigned short* __restrict__ resid,
                                             unsigned short* __restrict__ hout) {
    int tid = threadIdx.x;
    int l2 = tid & 31;
    int g = blockIdx.x / 6250;
    int lb = blockIdx.x - g * 6250;
    int node = lb * 8 + (tid >> 5);           // local node id
    size_t nb = (size_t)g * NN;
    const uint2* hpg = hp + nb * 32;
    int gn = (int)nb + node;
    int beg = off[gn], end = off[gn + 1];

    uint2 sv = hpg[(size_t)node * 32 + l2];
    float a0 = bflo(sv.x), a1 = bfhi(sv.x), a2 = bflo(sv.y), a3 = bfhi(sv.y);

    int e = beg;
    for (; e + 16 <= end; e += 16) {
        int s[16];
#pragma unroll
        for (int j = 0; j < 16; ++j) s[j] = (int)csrc[e + j];
        uint2 v[16];
#pragma unroll
        for (int j = 0; j < 16; ++j) v[j] = hpg[(size_t)s[j] * 32 + l2];
#pragma unroll
        for (int j = 0; j < 16; ++j) {
            a0 += bflo(v[j].x); a1 += bfhi(v[j].x);
            a2 += bflo(v[j].y); a3 += bfhi(v[j].y);
        }
    }
    for (; e + 4 <= end; e += 4) {
        int s[4];
#pragma unroll
        for (int j = 0; j < 4; ++j) s[j] = (int)csrc[e + j];
        uint2 v[4];
#pragma unroll
        for (int j = 0; j < 4; ++j) v[j] = hpg[(size_t)s[j] * 32 + l2];
#pragma unroll
        for (int j = 0; j < 4; ++j) {
            a0 += bflo(v[j].x); a1 += bfhi(v[j].x);
            a2 += bflo(v[j].y); a3 += bfhi(v[j].y);
        }
    }
    for (; e < end; ++e) {
        uint2 v = hpg[(size_t)csrc[e] * 32 + l2];
        a0 += bflo(v.x); a1 += bfhi(v.x);
        a2 += bflo(v.y); a3 += bfhi(v.y);
    }
    float dv = dinv[gn];
    float4 b = ((const float4*)bias)[l2];
    float o0 = fmaxf(a0 * dv + b.x, 0.f);
    float o1 = fmaxf(a1 * dv + b.y, 0.f);
    float o2 = fmaxf(a2 * dv + b.z, 0.f);
    float o3 = fmaxf(a3 * dv + b.w, 0.f);
    if (resid) {
        uint2 rv = ((const uint2*)resid)[(size_t)gn * 32 + l2];
        o0 += bflo(rv.x); o1 += bfhi(rv.x);
        o2 += bflo(rv.y); o3 += bfhi(rv.y);
    }
    uint2 ov;
    ov.x = packbf(o0, o1);
    ov.y = packbf(o2, o3);
    ((uint2*)hout)[(size_t)gn * 32 + l2] = ov;
}

// ---------------- Pooling (both graphs, inline segment search, zeroes head stats) ----

static __device__ __forceinline__ int lbound(const int* __restrict__ a, int key) {
    int lo = 0, hi = NN;
    while (lo < hi) { int mid = (lo + hi) >> 1; if (a[mid] < key) lo = mid + 1; else hi = mid; }
    return lo;
}

__global__ void k_pool(const unsigned short* __restrict__ h,
                       const int* __restrict__ b0, const int* __restrict__ b1,
                       float* __restrict__ pooled, float* __restrict__ stats) {
    int b = blockIdx.x;                  // 1024 blocks
    int g = b >> 9, lg = b & 511;
    int c = threadIdx.x;                 // 128 threads
    if (b == 0) {
        for (int i = c; i < 2048; i += 128) stats[i] = 0.f;
    }
    const int* batch = g ? b1 : b0;
    int beg = lbound(batch, lg);
    int end = lbound(batch, lg + 1);
    const unsigned short* hb = h + (size_t)g * NN * FHID;
    float s = 0.f;
    for (int i = beg; i < end; ++i) s += bf2f(hb[(size_t)i * FHID + c]);
    int cnt = end - beg;
    pooled[(size_t)b * FHID + c] = s / (float)(cnt > 0 ? cnt : 1);
}

// ---------------- Fused MLP / BN heads (1024 rows = both graphs) ----------------

__global__ void k_mlp(const float* __restrict__ A, const float* __restrict__ W,
                      const float* __restrict__ bias, float* __restrict__ out,
                      int K, int Nc, int act,
                      float* __restrict__ statsOut,
                      const float* __restrict__ statsIn,
                      const float* __restrict__ gIn, const float* __restrict__ beIn) {
    __shared__ float As[8 * 256];
    __shared__ float scl[256], shf[256];
    int n = threadIdx.x;                 // blockDim.x == Nc
    int r0 = blockIdx.x * 8;             // 128 blocks -> 1024 rows
    int g = blockIdx.x >> 6;
    if (statsIn && n < K) {
        const float* si = statsIn + g * 512;
        float m = si[n] * (1.f / 512.f);
        float var = si[K + n] * (1.f / 512.f) - m * m;
        float inv = 1.0f / sqrtf(var + 1e-5f);
        float s = gIn[n] * inv;
        scl[n] = s;
        shf[n] = beIn[n] - m * s;
    }
    __syncthreads();
    for (int idx = n; idx < 8 * K; idx += blockDim.x) {
        float v = A[(size_t)r0 * K + idx];
        if (statsIn) {
            int k = idx & (K - 1);       // K is 128 or 256
            v = fmaxf(v * scl[k] + shf[k], 0.f);   // relu(BN(.)) input transform
        }
        As[idx] = v;
    }
    __syncthreads();
    float bb = bias[n];
    float acc[8];
#pragma unroll
    for (int r = 0; r < 8; ++r) acc[r] = bb;
    for (int k = 0; k < K; ++k) {
        float w = W[(size_t)k * Nc + n];
#pragma unroll
        for (int r = 0; r < 8; ++r) acc[r] = fmaf(As[r * K + k], w, acc[r]);
    }
    if (statsOut) {
        float s = 0.f, q = 0.f;
#pragma unroll
        for (int r = 0; r < 8; ++r) { s += acc[r]; q += acc[r] * acc[r]; }
        atomicAdd(&statsOut[g * 512 + n], s);
        atomicAdd(&statsOut[g * 512 + Nc + n], q);
    }
#pragma unroll
    for (int r = 0; r < 8; ++r) {
        float v = acc[r];
        if (act) v = fmaxf(v, 0.f);
        out[(size_t)(r0 + r) * Nc + n] = v;
    }
}

__global__ void k_bnapply(const float* __restrict__ X, const float* __restrict__ stats,
                          const float* __restrict__ gamma, const float* __restrict__ beta,
                          float* __restrict__ out, int Nc, int act) {
    int i = blockIdx.x * 256 + threadIdx.x;          // 1024*Nc elements
    if (i >= 1024 * Nc) return;
    int c = i % Nc;
    int g = i / (512 * Nc);
    const float* st = stats + g * 512;
    float m = st[c] * (1.f / 512.f);
    float var = st[Nc + c] * (1.f / 512.f) - m * m;
    float inv = 1.0f / sqrtf(var + 1e-5f);
    float v = gamma[c] * (X[i] - m) * inv + beta[c];
    if (act) v = fmaxf(v, 0.f);
    out[i] = v;
}

// ---------------- Orchestration ----------------

extern "C" void kernel_launch(void* const* d_in, const int* in_sizes, int n_in,
                              void* d_out, int out_size, void* d_ws, size_t ws_size,
                              hipStream_t stream) {
    const float* x1 = (const float*)d_in[0];
    const float* x2 = (const float*)d_in[3];
    const int*   ei[2]    = {(const int*)d_in[1], (const int*)d_in[4]};
    const int*   batch[2] = {(const int*)d_in[2], (const int*)d_in[5]};
    const float* W[3]  = {(const float*)d_in[6], (const float*)d_in[8], (const float*)d_in[10]};
    const float* bb[3] = {(const float*)d_in[7], (const float*)d_in[9], (const float*)d_in[11]};
    const float* Wp1 = (const float*)d_in[12]; const float* bp1 = (const float*)d_in[13];
    const float* g1  = (const float*)d_in[14]; const float* be1 = (const float*)d_in[15];
    const float* Wp2 = (const float*)d_in[16]; const float* bp2 = (const float*)d_in[17];
    const float* g2  = (const float*)d_in[18]; const float* be2 = (const float*)d_in[19];
    const float* Wq1 = (const float*)d_in[20]; const float* bq1 = (const float*)d_in[21];
    const float* Wq2 = (const float*)d_in[22]; const float* bq2 = (const float*)d_in[23];

    char* ws = (char*)d_ws;
    size_t off = 0;
    auto alloc = [&](size_t bytes) -> void* {
        void* p = ws + off;
        off += (bytes + 255) & ~(size_t)255;
        return p;
    };
    unsigned short* h_cur  = (unsigned short*)alloc((size_t)NN2 * FHID * 2);  // bf16 state
    unsigned short* hp     = (unsigned short*)alloc((size_t)NN2 * FHID * 2);  // bf16 pre-agg
    unsigned short* csrc   = (unsigned short*)alloc((size_t)NE2 * 2);
    int*            csroff = (int*)alloc((size_t)(NN2 + 1) * 4);
    unsigned short* lrank  = (unsigned short*)alloc((size_t)NE2 * 2);
    unsigned*       pedge  = (unsigned*)alloc((size_t)NE2 * 4);
    int*            histG  = (int*)alloc((size_t)NHIST2 * 4);
    int*            histS  = (int*)alloc((size_t)NHIST2 * 4);
    float*          dinv   = (float*)alloc((size_t)100352 * 4);  // padded for gemm epilogue
    float*          pooled = (float*)alloc((size_t)2 * NG * FHID * 4);
    short*          Wf     = (short*)alloc((size_t)3 * 16384 * 2);
    float*          t1     = (float*)alloc((size_t)1024 * 256 * 4);
    float*          t2     = (float*)alloc((size_t)1024 * 256 * 4);
    float*          t3     = (float*)alloc((size_t)1024 * 128 * 4);
    float*          stats  = (float*)alloc(2048 * 4);  // [st1: 2g x 512][st2: 2g x 512]

    const int* src0 = ei[0];           const int* dst0 = ei[0] + NEDGE;
    const int* src1 = ei[1];           const int* dst1 = ei[1] + NEDGE;

    k_prepw<<<96, 64, 0, stream>>>(W[0], W[1], W[2], Wf);

    // merged atomic-free radix CSR build (both graphs), 512-node buckets
    k_bhist<<<NABLK2, 1024, 0, stream>>>(dst0, dst1, histG, lrank);
    s_scan_all<<<1, 1024, 0, stream>>>(histG, histS, NHIST2);
    k_part<<<NABLK2, 1024, 0, stream>>>(src0, dst0, src1, dst1, lrank, histS, pedge);
    k_csr<<<NBUCK2, 256, 0, stream>>>(pedge, histS, csroff, csrc, dinv);

    // encoder: merged gemm, merged two-graph aggregation
    for (int l = 0; l < 3; ++l) {
        const unsigned short* Abf = (l == 0) ? nullptr : h_cur;
        const unsigned short* resid = (l == 0) ? nullptr : h_cur;
        k_gemm<<<1564, 256, 0, stream>>>(x1, x2, Abf, Wf + (size_t)l * 16384, dinv, hp);
        k_agg<<<12500, 256, 0, stream>>>((const uint2*)hp, csroff, csrc, dinv,
                                         bb[l], resid, h_cur);
    }
    k_pool<<<1024, 128, 0, stream>>>(h_cur, batch[0], batch[1], pooled, stats);

    // merged heads (1024 rows, per-graph BN stats)
    float* outp = (float*)d_out;
    float* p_out = outp;                           // p1,p2 contiguous [1024,256]
    float* z_out = outp + (size_t)2 * NG * FPROJ;  // z1,z2 contiguous [1024,256]
    float* st1 = stats, *st2 = stats + 1024;
    k_mlp<<<128, 256, 0, stream>>>(pooled, Wp1, bp1, t1,
                                   128, 256, 0, st1, nullptr, nullptr, nullptr);
    k_mlp<<<128, 256, 0, stream>>>(t1, Wp2, bp2, t2,
                                   256, 256, 0, st2, st1, g1, be1);
    k_bnapply<<<1024, 256, 0, stream>>>(t2, st2, g2, be2, z_out, 256, 0);
    k_mlp<<<128, 128, 0, stream>>>(z_out, Wq1, bq1, t3,
                                   256, 128, 1, nullptr, nullptr, nullptr, nullptr);
    k_mlp<<<128, 256, 0, stream>>>(t3, Wq2, bq2, p_out,
                                   128, 256, 0, nullptr, nullptr, nullptr, nullptr);
}

// Round 11
// 732.000 us; speedup vs baseline: 1.1052x; 1.1052x over previous
//
#include <hip/hip_runtime.h>
#include <hip/hip_bf16.h>

#define NN     50000
#define NN2    100000
#define NEDGE  1600000
#define NE2    3200000
#define NG     512
#define FIN    128
#define FHID   128
#define FPROJ  256

// merged radix CSR build params — 512-node coarse buckets
#define BSH    9
#define BSZ    512
#define NBUCK  98
#define NBUCK2 196
#define EPB    8192
#define NABLK  196
#define NABLK2 392
#define NHIST2 (NBUCK2*NABLK2)   // 76,832
#define NSB1   ((NHIST2 + 255) / 256)   // 301 scan blocks

typedef __attribute__((ext_vector_type(8))) short short8;
typedef __attribute__((ext_vector_type(4))) float f32x4;

static __device__ __forceinline__ short f2bf(float f) {
    union { float f; unsigned u; } x; x.f = f;
    unsigned r = (x.u + 0x7FFFu + ((x.u >> 16) & 1u)) >> 16;
    return (short)(r & 0xFFFFu);
}
static __device__ __forceinline__ float bf2f(unsigned short u) {
    union { unsigned u; float f; } x; x.u = ((unsigned)u) << 16;
    return x.f;
}
static __device__ __forceinline__ float bflo(unsigned u) {
    union { unsigned u; float f; } x; x.u = u << 16; return x.f;
}
static __device__ __forceinline__ float bfhi(unsigned u) {
    union { unsigned u; float f; } x; x.u = u & 0xFFFF0000u; return x.f;
}
static __device__ __forceinline__ unsigned packbf(float a, float b) {
    return (unsigned)(unsigned short)f2bf(a) | ((unsigned)(unsigned short)f2bf(b) << 16);
}

// ---------------- merged CSR build (both graphs, atomic-free at device scope) ----

__global__ __launch_bounds__(1024) void k_bhist(const int* __restrict__ dst0,
                                                const int* __restrict__ dst1,
                                                int* __restrict__ histG,
                                                unsigned short* __restrict__ lrank) {
    __shared__ int h[NBUCK2];
    for (int j = threadIdx.x; j < NBUCK2; j += 1024) h[j] = 0;
    __syncthreads();
    int b = blockIdx.x;                  // 0..391
    int g = b / NABLK, blk = b % NABLK;
    const int* dst = g ? dst1 : dst0;
    int base = blk * EPB;
    int gb = g * NBUCK;
    for (int t = threadIdx.x; t < EPB; t += 1024) {
        int i = base + t;
        if (i < NEDGE)
            lrank[(size_t)g * NEDGE + i] =
                (unsigned short)atomicAdd(&h[gb + (dst[i] >> BSH)], 1);
    }
    __syncthreads();
    for (int j = threadIdx.x; j < NBUCK2; j += 1024)
        histG[(size_t)j * NABLK2 + b] = h[j];
}

// parallel 3-dispatch scan cascade
__global__ void s_scan256(const int* __restrict__ in, int* __restrict__ out,
                          int* __restrict__ bsum, int n) {
    __shared__ int s[256];
    int i = blockIdx.x * 256 + threadIdx.x;
    int v = (i < n) ? in[i] : 0;
    s[threadIdx.x] = v;
    for (int o = 1; o < 256; o <<= 1) {
        __syncthreads();
        int t = (threadIdx.x >= o) ? s[threadIdx.x - o] : 0;
        __syncthreads();
        s[threadIdx.x] += t;
    }
    __syncthreads();
    if (i < n) out[i] = s[threadIdx.x] - v;   // exclusive
    if (threadIdx.x == 255) bsum[blockIdx.x] = s[255];
}

__global__ __launch_bounds__(512) void s_scan_tail(int* __restrict__ bsum, int nb) {
    __shared__ int s[512];
    int v = (threadIdx.x < nb) ? bsum[threadIdx.x] : 0;
    s[threadIdx.x] = v;
    for (int o = 1; o < 512; o <<= 1) {
        __syncthreads();
        int t = (threadIdx.x >= o) ? s[threadIdx.x - o] : 0;
        __syncthreads();
        s[threadIdx.x] += t;
    }
    __syncthreads();
    if (threadIdx.x < nb) bsum[threadIdx.x] = s[threadIdx.x] - v;  // exclusive
}

__global__ void s_add(int* __restrict__ out, const int* __restrict__ bs, int n) {
    int i = blockIdx.x * 256 + threadIdx.x;
    if (i < n) out[i] += bs[blockIdx.x];
}

__global__ __launch_bounds__(1024) void k_part(const int* __restrict__ src0,
                                               const int* __restrict__ dst0,
                                               const int* __restrict__ src1,
                                               const int* __restrict__ dst1,
                                               const unsigned short* __restrict__ lrank,
                                               const int* __restrict__ histS,
                                               unsigned* __restrict__ pedge) {
    int b = blockIdx.x;
    int g = b / NABLK, blk = b % NABLK;
    const int* src = g ? src1 : src0;
    const int* dst = g ? dst1 : dst0;
    int base = blk * EPB;
    int gb = g * NBUCK;
    for (int t = threadIdx.x; t < EPB; t += 1024) {
        int i = base + t;
        if (i < NEDGE) {
            int d = dst[i];
            int pos = histS[(size_t)(gb + (d >> BSH)) * NABLK2 + b]
                      + (int)lrank[(size_t)g * NEDGE + i];
            pedge[pos] = (unsigned)src[i] | ((unsigned)(d & (BSZ - 1)) << 16);
        }
    }
}

// one block per 512-node bucket -> fine CSR (ushort srcs) + csroff + dinv
__global__ __launch_bounds__(256) void k_csr(const unsigned* __restrict__ pedge,
                                             const int* __restrict__ histS,
                                             int* __restrict__ csroff,
                                             unsigned short* __restrict__ csrc,
                                             float* __restrict__ dinv) {
    __shared__ int cnt[BSZ], off[BSZ], cur[BSZ];
    int k = blockIdx.x;                  // 0..195
    int g = k / NBUCK;
    int nl0 = (k - g * NBUCK) * BSZ;
    int beg = histS[(size_t)k * NABLK2];
    int end = (k == NBUCK2 - 1) ? NE2 : histS[(size_t)(k + 1) * NABLK2];
    for (int t = threadIdx.x; t < BSZ; t += 256) { cnt[t] = 0; cur[t] = 0; }
    __syncthreads();
    for (int e = beg + threadIdx.x; e < end; e += 256)
        atomicAdd(&cnt[(pedge[e] >> 16) & (BSZ - 1)], 1);
    __syncthreads();
    if (threadIdx.x == 0) {
        int s = 0;
        for (int j = 0; j < BSZ; ++j) { off[j] = s; s += cnt[j]; }
    }
    __syncthreads();
    for (int e = beg + threadIdx.x; e < end; e += 256) {
        unsigned v = pedge[e];
        int j = (v >> 16) & (BSZ - 1);
        int r = atomicAdd(&cur[j], 1);
        csrc[beg + off[j] + r] = (unsigned short)(v & 0xFFFFu);
    }
    __syncthreads();
    for (int t = threadIdx.x; t < BSZ; t += 256) {
        int nl = nl0 + t;
        if (nl < NN) {
            int gn = g * NN + nl;
            csroff[gn] = beg + off[t];
            dinv[gn] = 1.0f / sqrtf((float)(cnt[t] + 1));
        }
    }
    if (k == NBUCK2 - 1 && threadIdx.x == 0) csroff[NN2] = NE2;
}

// ---------------- MFMA GEMM over both graphs: hp[i,:] = bf16((A[i,:]@W)*dinv[i]) ----

__global__ void k_prepw(const float* __restrict__ W0, const float* __restrict__ W1,
                        const float* __restrict__ W2, short* __restrict__ Wf) {
    int b = blockIdx.x;                  // 96 blocks
    int l = b >> 5; b &= 31;
    const float* W = (l == 0) ? W0 : (l == 1) ? W1 : W2;
    int nt = b >> 2, kt = b & 3;
    int lane = threadIdx.x;
    int n = nt * 16 + (lane & 15);
    int kbase = kt * 32 + (lane >> 4) * 8;
    short8 v;
#pragma unroll
    for (int j = 0; j < 8; ++j) v[j] = f2bf(W[(kbase + j) * FHID + n]);
    *(short8*)(Wf + (size_t)l * 16384 + (size_t)((nt * 4 + kt) * 64 + lane) * 8) = v;
}

__global__ __launch_bounds__(256) void k_gemm(const float* __restrict__ x1,
                                              const float* __restrict__ x2,
                                              const unsigned short* __restrict__ Abf,
                                              const short* __restrict__ Wf,
                                              const float* __restrict__ dinv,
                                              unsigned short* __restrict__ hp) {
    int lane = threadIdx.x & 63;
    int wv = threadIdx.x >> 6;
    int quad = lane >> 4;
    int rowbase = blockIdx.x * 64 + wv * 16;    // 1564 blocks -> 100,096 rows
    int arow = rowbase + (lane & 15);
    if (arow >= NN2) arow = NN2 - 1;

    f32x4 acc[8];
#pragma unroll
    for (int i = 0; i < 8; ++i) acc[i] = (f32x4){0.f, 0.f, 0.f, 0.f};

#pragma unroll
    for (int kt = 0; kt < 4; ++kt) {
        short8 af;
        if (Abf) {
            af = *(const short8*)(Abf + (size_t)arow * FIN + kt * 32 + quad * 8);
        } else {
            const float* ap = (arow < NN ? x1 + (size_t)arow * FIN
                                         : x2 + (size_t)(arow - NN) * FIN)
                              + kt * 32 + quad * 8;
            float4 a0 = *(const float4*)ap;
            float4 a1 = *(const float4*)(ap + 4);
            af[0] = f2bf(a0.x); af[1] = f2bf(a0.y); af[2] = f2bf(a0.z); af[3] = f2bf(a0.w);
            af[4] = f2bf(a1.x); af[5] = f2bf(a1.y); af[6] = f2bf(a1.z); af[7] = f2bf(a1.w);
        }
#pragma unroll
        for (int nt = 0; nt < 8; ++nt) {
            short8 bf = *(const short8*)(Wf + (size_t)((nt * 4 + kt) * 64 + lane) * 8);
            acc[nt] = __builtin_amdgcn_mfma_f32_16x16x32_bf16(af, bf, acc[nt], 0, 0, 0);
        }
    }
    // C/D layout: col = lane&15, row = quad*4 + reg   [measured m89/m91]
    float4 dv = *(const float4*)(dinv + rowbase + quad * 4);
    float dvv[4] = {dv.x, dv.y, dv.z, dv.w};
    int col = lane & 15;
#pragma unroll
    for (int r = 0; r < 4; ++r) {
        int orow = rowbase + quad * 4 + r;
        if (orow < NN2) {
#pragma unroll
            for (int nt = 0; nt < 8; ++nt)
                hp[(size_t)orow * FHID + nt * 16 + col] =
                    (unsigned short)f2bf(acc[nt][r] * dvv[r]);
        }
    }
}

// ------- Aggregate full 128-feature row, BOTH graphs in one dispatch

__global__ __launch_bounds__(256) void k_agg(const uint2* __restrict__ hp,
                                             const int* __restrict__ off,
                                             const unsigned short* __restrict__ csrc,
                                             const float* __restrict__ dinv,
                                             const float* __restrict__ bias,
                                             const unsigned short* __restrict__ resid,
                                             unsigned short* __restrict__ hout) {
    int tid = threadIdx.x;
    int l2 = tid & 31;
    int g = blockIdx.x / 6250;
    int lb = blockIdx.x - g * 6250;
    int node = lb * 8 + (tid >> 5);           // local node id
    size_t nb = (size_t)g * NN;
    const uint2* hpg = hp + nb * 32;
    int gn = (int)nb + node;
    int beg = off[gn], end = off[gn + 1];

    uint2 sv = hpg[(size_t)node * 32 + l2];
    float a0 = bflo(sv.x), a1 = bfhi(sv.x), a2 = bflo(sv.y), a3 = bfhi(sv.y);

    int e = beg;
    for (; e + 16 <= end; e += 16) {
        int s[16];
#pragma unroll
        for (int j = 0; j < 16; ++j) s[j] = (int)csrc[e + j];
        uint2 v[16];
#pragma unroll
        for (int j = 0; j < 16; ++j) v[j] = hpg[(size_t)s[j] * 32 + l2];
#pragma unroll
        for (int j = 0; j < 16; ++j) {
            a0 += bflo(v[j].x); a1 += bfhi(v[j].x);
            a2 += bflo(v[j].y); a3 += bfhi(v[j].y);
        }
    }
    for (; e + 4 <= end; e += 4) {
        int s[4];
#pragma unroll
        for (int j = 0; j < 4; ++j) s[j] = (int)csrc[e + j];
        uint2 v[4];
#pragma unroll
        for (int j = 0; j < 4; ++j) v[j] = hpg[(size_t)s[j] * 32 + l2];
#pragma unroll
        for (int j = 0; j < 4; ++j) {
            a0 += bflo(v[j].x); a1 += bfhi(v[j].x);
            a2 += bflo(v[j].y); a3 += bfhi(v[j].y);
        }
    }
    for (; e < end; ++e) {
        uint2 v = hpg[(size_t)csrc[e] * 32 + l2];
        a0 += bflo(v.x); a1 += bfhi(v.x);
        a2 += bflo(v.y); a3 += bfhi(v.y);
    }
    float dv = dinv[gn];
    float4 b = ((const float4*)bias)[l2];
    float o0 = fmaxf(a0 * dv + b.x, 0.f);
    float o1 = fmaxf(a1 * dv + b.y, 0.f);
    float o2 = fmaxf(a2 * dv + b.z, 0.f);
    float o3 = fmaxf(a3 * dv + b.w, 0.f);
    if (resid) {
        uint2 rv = ((const uint2*)resid)[(size_t)gn * 32 + l2];
        o0 += bflo(rv.x); o1 += bfhi(rv.x);
        o2 += bflo(rv.y); o3 += bfhi(rv.y);
    }
    uint2 ov;
    ov.x = packbf(o0, o1);
    ov.y = packbf(o2, o3);
    ((uint2*)hout)[(size_t)gn * 32 + l2] = ov;
}

// ---------------- Pooling (both graphs, inline segment search, zeroes head stats) ----

static __device__ __forceinline__ int lbound(const int* __restrict__ a, int key) {
    int lo = 0, hi = NN;
    while (lo < hi) { int mid = (lo + hi) >> 1; if (a[mid] < key) lo = mid + 1; else hi = mid; }
    return lo;
}

__global__ void k_pool(const unsigned short* __restrict__ h,
                       const int* __restrict__ b0, const int* __restrict__ b1,
                       float* __restrict__ pooled, float* __restrict__ stats) {
    int b = blockIdx.x;                  // 1024 blocks
    int g = b >> 9, lg = b & 511;
    int c = threadIdx.x;                 // 128 threads
    if (b == 0) {
        for (int i = c; i < 2048; i += 128) stats[i] = 0.f;
    }
    const int* batch = g ? b1 : b0;
    int beg = lbound(batch, lg);
    int end = lbound(batch, lg + 1);
    const unsigned short* hb = h + (size_t)g * NN * FHID;
    float s = 0.f;
    for (int i = beg; i < end; ++i) s += bf2f(hb[(size_t)i * FHID + c]);
    int cnt = end - beg;
    pooled[(size_t)b * FHID + c] = s / (float)(cnt > 0 ? cnt : 1);
}

// ---------------- Fused MLP / BN heads (1024 rows = both graphs) ----------------

__global__ void k_mlp(const float* __restrict__ A, const float* __restrict__ W,
                      const float* __restrict__ bias, float* __restrict__ out,
                      int K, int Nc, int act,
                      float* __restrict__ statsOut,
                      const float* __restrict__ statsIn,
                      const float* __restrict__ gIn, const float* __restrict__ beIn) {
    __shared__ float As[8 * 256];
    __shared__ float scl[256], shf[256];
    int n = threadIdx.x;                 // blockDim.x == Nc
    int r0 = blockIdx.x * 8;             // 128 blocks -> 1024 rows
    int g = blockIdx.x >> 6;
    if (statsIn && n < K) {
        const float* si = statsIn + g * 512;
        float m = si[n] * (1.f / 512.f);
        float var = si[K + n] * (1.f / 512.f) - m * m;
        float inv = 1.0f / sqrtf(var + 1e-5f);
        float s = gIn[n] * inv;
        scl[n] = s;
        shf[n] = beIn[n] - m * s;
    }
    __syncthreads();
    for (int idx = n; idx < 8 * K; idx += blockDim.x) {
        float v = A[(size_t)r0 * K + idx];
        if (statsIn) {
            int k = idx & (K - 1);       // K is 128 or 256
            v = fmaxf(v * scl[k] + shf[k], 0.f);   // relu(BN(.)) input transform
        }
        As[idx] = v;
    }
    __syncthreads();
    float bb = bias[n];
    float acc[8];
#pragma unroll
    for (int r = 0; r < 8; ++r) acc[r] = bb;
    for (int k = 0; k < K; ++k) {
        float w = W[(size_t)k * Nc + n];
#pragma unroll
        for (int r = 0; r < 8; ++r) acc[r] = fmaf(As[r * K + k], w, acc[r]);
    }
    if (statsOut) {
        float s = 0.f, q = 0.f;
#pragma unroll
        for (int r = 0; r < 8; ++r) { s += acc[r]; q += acc[r] * acc[r]; }
        atomicAdd(&statsOut[g * 512 + n], s);
        atomicAdd(&statsOut[g * 512 + Nc + n], q);
    }
#pragma unroll
    for (int r = 0; r < 8; ++r) {
        float v = acc[r];
        if (act) v = fmaxf(v, 0.f);
        out[(size_t)(r0 + r) * Nc + n] = v;
    }
}

__global__ void k_bnapply(const float* __restrict__ X, const float* __restrict__ stats,
                          const float* __restrict__ gamma, const float* __restrict__ beta,
                          float* __restrict__ out, int Nc, int act) {
    int i = blockIdx.x * 256 + threadIdx.x;          // 1024*Nc elements
    if (i >= 1024 * Nc) return;
    int c = i % Nc;
    int g = i / (512 * Nc);
    const float* st = stats + g * 512;
    float m = st[c] * (1.f / 512.f);
    float var = st[Nc + c] * (1.f / 512.f) - m * m;
    float inv = 1.0f / sqrtf(var + 1e-5f);
    float v = gamma[c] * (X[i] - m) * inv + beta[c];
    if (act) v = fmaxf(v, 0.f);
    out[i] = v;
}

// ---------------- Orchestration ----------------

extern "C" void kernel_launch(void* const* d_in, const int* in_sizes, int n_in,
                              void* d_out, int out_size, void* d_ws, size_t ws_size,
                              hipStream_t stream) {
    const float* x1 = (const float*)d_in[0];
    const float* x2 = (const float*)d_in[3];
    const int*   ei[2]    = {(const int*)d_in[1], (const int*)d_in[4]};
    const int*   batch[2] = {(const int*)d_in[2], (const int*)d_in[5]};
    const float* W[3]  = {(const float*)d_in[6], (const float*)d_in[8], (const float*)d_in[10]};
    const float* bb[3] = {(const float*)d_in[7], (const float*)d_in[9], (const float*)d_in[11]};
    const float* Wp1 = (const float*)d_in[12]; const float* bp1 = (const float*)d_in[13];
    const float* g1  = (const float*)d_in[14]; const float* be1 = (const float*)d_in[15];
    const float* Wp2 = (const float*)d_in[16]; const float* bp2 = (const float*)d_in[17];
    const float* g2  = (const float*)d_in[18]; const float* be2 = (const float*)d_in[19];
    const float* Wq1 = (const float*)d_in[20]; const float* bq1 = (const float*)d_in[21];
    const float* Wq2 = (const float*)d_in[22]; const float* bq2 = (const float*)d_in[23];

    char* ws = (char*)d_ws;
    size_t off = 0;
    auto alloc = [&](size_t bytes) -> void* {
        void* p = ws + off;
        off += (bytes + 255) & ~(size_t)255;
        return p;
    };
    unsigned short* h_cur  = (unsigned short*)alloc((size_t)NN2 * FHID * 2);  // bf16 state
    unsigned short* hp     = (unsigned short*)alloc((size_t)NN2 * FHID * 2);  // bf16 pre-agg
    unsigned short* csrc   = (unsigned short*)alloc((size_t)NE2 * 2);
    int*            csroff = (int*)alloc((size_t)(NN2 + 1) * 4);
    unsigned short* lrank  = (unsigned short*)alloc((size_t)NE2 * 2);
    unsigned*       pedge  = (unsigned*)alloc((size_t)NE2 * 4);
    int*            histG  = (int*)alloc((size_t)NHIST2 * 4);
    int*            histS  = (int*)alloc((size_t)NHIST2 * 4);
    int*            bsum   = (int*)alloc(512 * 4);
    float*          dinv   = (float*)alloc((size_t)100352 * 4);  // padded for gemm epilogue
    float*          pooled = (float*)alloc((size_t)2 * NG * FHID * 4);
    short*          Wf     = (short*)alloc((size_t)3 * 16384 * 2);
    float*          t1     = (float*)alloc((size_t)1024 * 256 * 4);
    float*          t2     = (float*)alloc((size_t)1024 * 256 * 4);
    float*          t3     = (float*)alloc((size_t)1024 * 128 * 4);
    float*          stats  = (float*)alloc(2048 * 4);  // [st1: 2g x 512][st2: 2g x 512]

    const int* src0 = ei[0];           const int* dst0 = ei[0] + NEDGE;
    const int* src1 = ei[1];           const int* dst1 = ei[1] + NEDGE;

    k_prepw<<<96, 64, 0, stream>>>(W[0], W[1], W[2], Wf);

    // merged atomic-free radix CSR build (both graphs), 512-node buckets
    k_bhist<<<NABLK2, 1024, 0, stream>>>(dst0, dst1, histG, lrank);
    s_scan256<<<NSB1, 256, 0, stream>>>(histG, histS, bsum, NHIST2);
    s_scan_tail<<<1, 512, 0, stream>>>(bsum, NSB1);
    s_add<<<NSB1, 256, 0, stream>>>(histS, bsum, NHIST2);
    k_part<<<NABLK2, 1024, 0, stream>>>(src0, dst0, src1, dst1, lrank, histS, pedge);
    k_csr<<<NBUCK2, 256, 0, stream>>>(pedge, histS, csroff, csrc, dinv);

    // encoder: merged gemm, merged two-graph aggregation
    for (int l = 0; l < 3; ++l) {
        const unsigned short* Abf = (l == 0) ? nullptr : h_cur;
        const unsigned short* resid = (l == 0) ? nullptr : h_cur;
        k_gemm<<<1564, 256, 0, stream>>>(x1, x2, Abf, Wf + (size_t)l * 16384, dinv, hp);
        k_agg<<<12500, 256, 0, stream>>>((const uint2*)hp, csroff, csrc, dinv,
                                         bb[l], resid, h_cur);
    }
    k_pool<<<1024, 128, 0, stream>>>(h_cur, batch[0], batch[1], pooled, stats);

    // merged heads (1024 rows, per-graph BN stats)
    float* outp = (float*)d_out;
    float* p_out = outp;                           // p1,p2 contiguous [1024,256]
    float* z_out = outp + (size_t)2 * NG * FPROJ;  // z1,z2 contiguous [1024,256]
    float* st1 = stats, *st2 = stats + 1024;
    k_mlp<<<128, 256, 0, stream>>>(pooled, Wp1, bp1, t1,
                                   128, 256, 0, st1, nullptr, nullptr, nullptr);
    k_mlp<<<128, 256, 0, stream>>>(t1, Wp2, bp2, t2,
                                   256, 256, 0, st2, st1, g1, be1);
    k_bnapply<<<1024, 256, 0, stream>>>(t2, st2, g2, be2, z_out, 256, 0);
    k_mlp<<<128, 128, 0, stream>>>(z_out, Wq1, bq1, t3,
                                   256, 128, 1, nullptr, nullptr, nullptr, nullptr);
    k_mlp<<<128, 256, 0, stream>>>(t3, Wq2, bq2, p_out,
                                   128, 256, 0, nullptr, nullptr, nullptr, nullptr);
}